// Round 13
// baseline (532.892 us; speedup 1.0000x reference)
//
#include <hip/hip_runtime.h>
#include <cmath>

#define NN   20000   // nodes
#define NE   320000  // edges (before self-loops)
#define IND  256
#define HIDD 64
#define NH   4
#define CD   64
#define HC   256     // NH*CD
#define DFFD 128
#define NL   4
#define NPB  8       // nodes per layer block

// All float tensors are float32 (verified R1 vs R2). Output f32.
// R6 lesson: occupancy beats LDS-op reduction in this barrier-heavy regime.
// R7 lesson: profiled dispatch dur is inflated vs wall clock; trust totals.
// R9 lesson: gather is latency-bound (deg~17), lever is resident waves.
// R10+R12 lesson: this kernel needs >=64 VGPRs; launch_bounds that squeezes below
//   that -> scratch spill (+17MB WRITE, +14MB FETCH). (256,4) gives budget 128;
//   residency is then LDS/VGPR-limited (16KB,64VGPR -> 8 blk/CU), not bound-limited.
// R11 lesson: smaller blocks pack better (tail + latency hiding).

static __device__ __forceinline__ float lrelu(float v) { return v > 0.f ? v : 0.2f * v; }
static __device__ __forceinline__ float wsum(float v) { for (int k = 32; k; k >>= 1) v += __shfl_xor(v, k); return v; }
static __device__ __forceinline__ float wmax(float v) { for (int k = 32; k; k >>= 1) v = fmaxf(v, __shfl_xor(v, k)); return v; }
static __device__ __forceinline__ void fma4(float4& a, const float4& v, float s) {
    a.x += v.x * s; a.y += v.y * s; a.z += v.z * s; a.w += v.w * s;
}

// ---- ws_all[l][r][k]: r=0..3 -> Wc_head@att_src, r=4..7 -> Wc_head@att_dst ----
__global__ void ws_kernel(const float* __restrict__ Wc, const float* __restrict__ att_src,
                          const float* __restrict__ att_dst, float* __restrict__ ws_all) {
    int idx = blockIdx.x * 256 + threadIdx.x;   // 0..2047 = L*8*64
    int l = idx >> 9, r = (idx >> 6) & 7, k = idx & 63;
    int hh = r & 3;
    const float* att = ((r & 4) ? att_dst : att_src) + (size_t)l * NH * CD + hh * CD;
    const float* wrow = Wc + (size_t)l * HIDD * HC + (size_t)k * HC + hh * CD;
    float s = 0.f;
    for (int c = 0; c < CD; ++c) s += wrow[c] * att[c];
    ws_all[idx] = s;
}

// ---- W1eff[l][h*64+k][f] = sum_c Wc[l][k][h*64+c] * W1[l][h*64+c][f] ----
__global__ void w1eff_kernel(const float* __restrict__ Wc, const float* __restrict__ W1,
                             float* __restrict__ W1eff) {
    const int b = blockIdx.x;               // 0..NL*256-1
    const int l = b >> 8, hk = b & 255, hh = hk >> 6, kl = hk & 63;
    const int f = threadIdx.x;              // 0..127
    const float* wc = Wc + (size_t)l * HIDD * HC + (size_t)kl * HC + hh * 64;
    const float* w1 = W1 + (size_t)l * HC * DFFD + (size_t)(hh * 64) * DFFD + f;
    float s = 0.f;
#pragma unroll 4
    for (int c = 0; c < 64; ++c) s += wc[c] * w1[(size_t)c * DFFD];
    W1eff[(size_t)l * HC * DFFD + (size_t)hk * DFFD + f] = s;
}

// ---- b1eff[l][f] = b1[l][f] + sum_c bc[l][c] * W1[l][c][f] ----
__global__ void b1eff_kernel(const float* __restrict__ bc, const float* __restrict__ W1,
                             const float* __restrict__ b1, float* __restrict__ b1eff) {
    const int l = blockIdx.x, f = threadIdx.x;   // NL blocks x 128 threads
    const float* w1 = W1 + (size_t)l * HC * DFFD + f;
    const float* bcl = bc + (size_t)l * HC;
    float s = b1[(size_t)l * DFFD + f];
    for (int c = 0; c < HC; ++c) s += bcl[c] * w1[(size_t)c * DFFD];
    b1eff[l * DFFD + f] = s;
}

// ---- embed: h = (x @ We + be) * 8, fused layer-0 attention dots; 16 nodes/block ----
__global__ __launch_bounds__(256) void embed_kernel(const float* __restrict__ x,
                                                    const float* __restrict__ We,
                                                    const float* __restrict__ be,
                                                    const float* __restrict__ ws_all,
                                                    float* __restrict__ h,
                                                    float* __restrict__ a_s, float* __restrict__ a_d) {
    __shared__ float s_x[16 * IND];   // 16KB
    const int base = blockIdx.x * 16, t = threadIdx.x;
    for (int idx = t; idx < 16 * IND / 4; idx += 256)
        ((float4*)s_x)[idx] = ((const float4*)(x + (size_t)base * IND))[idx];
    __syncthreads();
    const int c = t & 63, g = t >> 6;   // wave g: nodes 4g..4g+3, lane = channel c
    float acc[4] = {0.f, 0.f, 0.f, 0.f};
    const float4* sx4 = (const float4*)s_x;
#pragma unroll 2
    for (int k4 = 0; k4 < IND / 4; ++k4) {
        float w0 = We[(4 * k4 + 0) * HIDD + c];
        float w1 = We[(4 * k4 + 1) * HIDD + c];
        float w2 = We[(4 * k4 + 2) * HIDD + c];
        float w3 = We[(4 * k4 + 3) * HIDD + c];
#pragma unroll
        for (int i = 0; i < 4; ++i) {
            float4 v = sx4[(4 * g + i) * (IND / 4) + k4];
            acc[i] += v.x * w0 + v.y * w1 + v.z * w2 + v.w * w3;
        }
    }
    float bias = be[c];
    float wr[8];
#pragma unroll
    for (int r = 0; r < 8; ++r) wr[r] = ws_all[r * 64 + c];   // layer 0
#pragma unroll
    for (int i = 0; i < 4; ++i) {
        int node = base + 4 * g + i;
        float hv = (acc[i] + bias) * 8.0f;
        h[(size_t)node * HIDD + c] = hv;
        float s0 = wsum(hv * wr[0]), s1 = wsum(hv * wr[1]);
        float s2 = wsum(hv * wr[2]), s3 = wsum(hv * wr[3]);
        float s4 = wsum(hv * wr[4]), s5 = wsum(hv * wr[5]);
        float s6 = wsum(hv * wr[6]), s7 = wsum(hv * wr[7]);
        if (c == 0) {
            ((float4*)a_s)[node] = make_float4(s0, s1, s2, s3);
            ((float4*)a_d)[node] = make_float4(s4, s5, s6, s7);
        }
    }
}

// ---------------- CSR build ----------------
__global__ void init_deg(int* __restrict__ deg, int* __restrict__ cursor) {
    int i = blockIdx.x * blockDim.x + threadIdx.x;
    if (i < NN) { deg[i] = 1; cursor[i] = 0; }   // self-loop
}

__global__ void count_edges(const int* __restrict__ ei, int* __restrict__ deg) {
    int e = blockIdx.x * blockDim.x + threadIdx.x;
    if (e < NE) atomicAdd(&deg[ei[NE + e]], 1);
}

__global__ void scan_kernel(const int* __restrict__ deg, int* __restrict__ rowptr) {
    __shared__ int part[1024];
    const int t = threadIdx.x;
    const int CH = (NN + 1023) / 1024;
    int lo = t * CH, hi = lo + CH; if (hi > NN) hi = NN;
    int s = 0;
    for (int i = lo; i < hi; ++i) s += deg[i];
    part[t] = s;
    __syncthreads();
    for (int off = 1; off < 1024; off <<= 1) {
        int v = 0;
        if (t >= off) v = part[t - off];
        __syncthreads();
        if (t >= off) part[t] += v;
        __syncthreads();
    }
    int base = (t == 0) ? 0 : part[t - 1];
    for (int i = lo; i < hi; ++i) { rowptr[i] = base; base += deg[i]; }
    if (lo <= NN - 1 && NN - 1 < hi) rowptr[NN] = base;
}

__global__ void scatter_edges(const int* __restrict__ ei, const int* __restrict__ rowptr,
                              int* __restrict__ cursor, int* __restrict__ csr_src) {
    int e = blockIdx.x * blockDim.x + threadIdx.x;
    if (e < NE) {
        int s = ei[e], d = ei[NE + e];
        int pos = atomicAdd(&cursor[d], 1);
        csr_src[rowptr[d] + pos] = s;
    } else if (e < NE + NN) {
        int i = e - NE;
        int pos = atomicAdd(&cursor[i], 1);
        csr_src[rowptr[i] + pos] = i;
    }
}

// ---- fused layer: gather/softmax-aggregate -> GEMM1 -> GEMM2+LN+res ----
// 8 nodes/block, 2500 blocks. LDS: s_in 8KB + s_buf 8KB = 16KB.
// __launch_bounds__(256,4): VGPR budget 128 >= natural ~64 (no spill);
// residency = min(LDS 10, VGPR 8) = 8 blk/CU.
__global__ __launch_bounds__(256, 4) void layer_kernel(
    const float* __restrict__ h_in, const float* __restrict__ a_s_in, const float* __restrict__ a_d_in,
    const int* __restrict__ rowptr, const int* __restrict__ csr_src,
    const float* __restrict__ W1eff, const float* __restrict__ b1eff,
    const float* __restrict__ W2, const float* __restrict__ b2,
    const float* __restrict__ ln_g, const float* __restrict__ ln_b,
    const float* __restrict__ ws_next,
    float* __restrict__ h_out, float* __restrict__ a_s_out, float* __restrict__ a_d_out) {
    __shared__ float s_in[NPB * HC];  // 8KB aggregated node vectors
    __shared__ float s_buf[2048];     // 8KB: gather scratch -> W1eff k-tile -> mid
    const int base = blockIdx.x * NPB, t = threadIdx.x, wave = t >> 6, lane = t & 63;

    // ---- phase 1: softmax-attention aggregation, wave-synchronous, 2 nodes/wave ----
    // lane = (eg = lane>>4, cg = lane&15); b128 load covers 4 edges x 4 channels;
    // eg-butterfly (shfl_xor 16/32) completes channel sums.
    {
        int*    s_src = (int*)s_buf + wave * 64;             // per-wave [64] (1KB total)
        float4* s_w   = (float4*)(s_buf + 256) + wave * 64;  // per-wave [64] (4KB total)
        const float4* as4 = (const float4*)a_s_in;
        const float4* h4  = (const float4*)h_in;
        const int eg = lane >> 4, cg = lane & 15;
        for (int nd = 0; nd < 2; ++nd) {
            const int node = base + wave * 2 + nd;
            const int lo = rowptr[node], n = rowptr[node + 1] - lo;
            const float4 ad = ((const float4*)a_d_in)[node];
            float4 a0 = make_float4(0.f, 0.f, 0.f, 0.f);
            float4 a1 = a0, a2 = a0, a3 = a0;
            if (n <= 64) {
                float e0 = -1e30f, e1 = -1e30f, e2 = -1e30f, e3 = -1e30f;
                if (lane < n) {
                    int s = csr_src[lo + lane];
                    s_src[lane] = s;
                    float4 a = as4[s];
                    e0 = lrelu(a.x + ad.x); e1 = lrelu(a.y + ad.y);
                    e2 = lrelu(a.z + ad.z); e3 = lrelu(a.w + ad.w);
                }
                float M0 = wmax(e0), M1 = wmax(e1), M2 = wmax(e2), M3 = wmax(e3);
                float p0 = __expf(e0 - M0), p1 = __expf(e1 - M1);
                float p2 = __expf(e2 - M2), p3 = __expf(e3 - M3);   // inactive -> 0
                float iz0 = 1.f / (wsum(p0) + 1e-16f), iz1 = 1.f / (wsum(p1) + 1e-16f);
                float iz2 = 1.f / (wsum(p2) + 1e-16f), iz3 = 1.f / (wsum(p3) + 1e-16f);
                if (lane < n) s_w[lane] = make_float4(p0 * iz0, p1 * iz1, p2 * iz2, p3 * iz3);
                const int n8 = (n + 7) & ~7;
                if (lane >= n && lane < n8) {   // zero-weight padding, guard-free loop
                    s_src[lane] = s_src[0];
                    s_w[lane] = make_float4(0.f, 0.f, 0.f, 0.f);
                }
                for (int j = 0; j < n8; j += 8) {   // 8 edges in flight per iter
                    int sA = s_src[j + eg],     sB = s_src[j + 4 + eg];
                    float4 vA = h4[(size_t)sA * 16 + cg];
                    float4 vB = h4[(size_t)sB * 16 + cg];
                    float4 wA = s_w[j + eg],    wB = s_w[j + 4 + eg];
                    fma4(a0, vA, wA.x); fma4(a1, vA, wA.y); fma4(a2, vA, wA.z); fma4(a3, vA, wA.w);
                    fma4(a0, vB, wB.x); fma4(a1, vB, wB.y); fma4(a2, vB, wB.z); fma4(a3, vB, wB.w);
                }
            } else {
                // slow path (deg > 64): two-pass softmax, then chunked b128 gather
                float m0 = -1e30f, m1 = -1e30f, m2 = -1e30f, m3 = -1e30f;
                for (int j = lane; j < n; j += 64) {
                    int s = csr_src[lo + j];
                    float4 a = as4[s];
                    m0 = fmaxf(m0, lrelu(a.x + ad.x)); m1 = fmaxf(m1, lrelu(a.y + ad.y));
                    m2 = fmaxf(m2, lrelu(a.z + ad.z)); m3 = fmaxf(m3, lrelu(a.w + ad.w));
                }
                m0 = wmax(m0); m1 = wmax(m1); m2 = wmax(m2); m3 = wmax(m3);
                float z0 = 0.f, z1 = 0.f, z2 = 0.f, z3 = 0.f;
                for (int j = lane; j < n; j += 64) {
                    int s = csr_src[lo + j];
                    float4 a = as4[s];
                    z0 += __expf(lrelu(a.x + ad.x) - m0); z1 += __expf(lrelu(a.y + ad.y) - m1);
                    z2 += __expf(lrelu(a.z + ad.z) - m2); z3 += __expf(lrelu(a.w + ad.w) - m3);
                }
                float iz0 = 1.f / (wsum(z0) + 1e-16f), iz1 = 1.f / (wsum(z1) + 1e-16f);
                float iz2 = 1.f / (wsum(z2) + 1e-16f), iz3 = 1.f / (wsum(z3) + 1e-16f);
                for (int cb = 0; cb < n; cb += 64) {
                    int nn = n - cb; if (nn > 64) nn = 64;
                    if (lane < nn) {
                        int s = csr_src[lo + cb + lane];
                        s_src[lane] = s;
                        float4 a = as4[s];
                        s_w[lane] = make_float4(__expf(lrelu(a.x + ad.x) - m0) * iz0,
                                                __expf(lrelu(a.y + ad.y) - m1) * iz1,
                                                __expf(lrelu(a.z + ad.z) - m2) * iz2,
                                                __expf(lrelu(a.w + ad.w) - m3) * iz3);
                    }
                    const int nn8 = (nn + 7) & ~7;   // <= 64
                    if (lane >= nn && lane < nn8) {
                        s_src[lane] = s_src[0];
                        s_w[lane] = make_float4(0.f, 0.f, 0.f, 0.f);
                    }
                    for (int j = 0; j < nn8; j += 8) {
                        int sA = s_src[j + eg],     sB = s_src[j + 4 + eg];
                        float4 vA = h4[(size_t)sA * 16 + cg];
                        float4 vB = h4[(size_t)sB * 16 + cg];
                        float4 wA = s_w[j + eg],    wB = s_w[j + 4 + eg];
                        fma4(a0, vA, wA.x); fma4(a1, vA, wA.y); fma4(a2, vA, wA.z); fma4(a3, vA, wA.w);
                        fma4(a0, vB, wB.x); fma4(a1, vB, wB.y); fma4(a2, vB, wB.z); fma4(a3, vB, wB.w);
                    }
                }
            }
            // butterfly over eg bits (lanes 16/32 apart share channel group cg)
#pragma unroll
            for (int m = 16; m <= 32; m <<= 1) {
                a0.x += __shfl_xor(a0.x, m); a0.y += __shfl_xor(a0.y, m);
                a0.z += __shfl_xor(a0.z, m); a0.w += __shfl_xor(a0.w, m);
                a1.x += __shfl_xor(a1.x, m); a1.y += __shfl_xor(a1.y, m);
                a1.z += __shfl_xor(a1.z, m); a1.w += __shfl_xor(a1.w, m);
                a2.x += __shfl_xor(a2.x, m); a2.y += __shfl_xor(a2.y, m);
                a2.z += __shfl_xor(a2.z, m); a2.w += __shfl_xor(a2.w, m);
                a3.x += __shfl_xor(a3.x, m); a3.y += __shfl_xor(a3.y, m);
                a3.z += __shfl_xor(a3.z, m); a3.w += __shfl_xor(a3.w, m);
            }
            const int r = wave * 2 + nd;
            float4* si4 = (float4*)s_in;
            float4 outv = (eg == 0) ? a0 : (eg == 1) ? a1 : (eg == 2) ? a2 : a3;
            si4[r * 64 + lane] = outv;   // channel block eg*64 + 4*cg  == lane*4
        }
    }
    __syncthreads();

    // ---- phase 2: GEMM1 mid = gelu(s_in @ W1eff + b1eff); 1 node x 4 f per thread;
    //      W1eff staged in 16 LDS k-tiles of 16x128 (8KB each) ----
    const int fg = t & 31, ng = t >> 5;   // f = 4*fg.., node ng (0..7)
    float4 acc1 = make_float4(0.f, 0.f, 0.f, 0.f);
    {
        const float4* si4 = (const float4*)s_in;
        float4* sB4 = (float4*)s_buf;
        for (int kt = 0; kt < 16; ++kt) {
            __syncthreads();   // prior s_buf readers done (kt=0: gather scratch)
            const float4* gsrc = (const float4*)(W1eff + (size_t)kt * 16 * DFFD);
            for (int idx = t; idx < 512; idx += 256) sB4[idx] = gsrc[idx];
            __syncthreads();
#pragma unroll
            for (int k4 = 0; k4 < 4; ++k4) {
                float4 w0 = sB4[(4 * k4 + 0) * 32 + fg];   // W1eff[k][4fg..4fg+3]
                float4 w1 = sB4[(4 * k4 + 1) * 32 + fg];
                float4 w2 = sB4[(4 * k4 + 2) * 32 + fg];
                float4 w3 = sB4[(4 * k4 + 3) * 32 + fg];
                float4 v = si4[ng * 64 + kt * 4 + k4];   // half-wave uniform broadcast
                acc1.x += v.x * w0.x + v.y * w1.x + v.z * w2.x + v.w * w3.x;
                acc1.y += v.x * w0.y + v.y * w1.y + v.z * w2.y + v.w * w3.y;
                acc1.z += v.x * w0.z + v.y * w1.z + v.z * w2.z + v.w * w3.z;
                acc1.w += v.x * w0.w + v.y * w1.w + v.z * w2.w + v.w * w3.w;
            }
        }
    }
    __syncthreads();   // last tile consumed; s_buf becomes mid
    {
        float4 bb = *(const float4*)(b1eff + 4 * fg);
        float dx = acc1.x + bb.x, dy = acc1.y + bb.y;
        float dz = acc1.z + bb.z, dw = acc1.w + bb.w;
        ((float4*)s_buf)[ng * 32 + fg] = make_float4(
            0.5f * dx * (1.f + erff(dx * 0.70710678118654752f)),
            0.5f * dy * (1.f + erff(dy * 0.70710678118654752f)),
            0.5f * dz * (1.f + erff(dz * 0.70710678118654752f)),
            0.5f * dw * (1.f + erff(dw * 0.70710678118654752f)));
    }
    __syncthreads();

    // ---- phase 3: GEMM2 + LN + residual + next-layer attdots; 2 nodes/wave ----
    {
        const int w = t >> 6;   // wave w -> nodes 2w..2w+1, lane = channel
        float acc[2] = {0.f, 0.f};
        const float4* sm4 = (const float4*)s_buf;
#pragma unroll 4
        for (int k4 = 0; k4 < 32; ++k4) {
            float w0 = W2[(4 * k4 + 0) * HIDD + lane];
            float w1 = W2[(4 * k4 + 1) * HIDD + lane];
            float w2 = W2[(4 * k4 + 2) * HIDD + lane];
            float w3 = W2[(4 * k4 + 3) * HIDD + lane];
#pragma unroll
            for (int i = 0; i < 2; ++i) {
                float4 v = sm4[(2 * w + i) * 32 + k4];   // wave-uniform broadcast
                acc[i] += v.x * w0 + v.y * w1 + v.z * w2 + v.w * w3;
            }
        }
        const float b2c = b2[lane], gc = ln_g[lane], bbc = ln_b[lane];
        float wr[8];
#pragma unroll
        for (int r = 0; r < 8; ++r) wr[r] = 0.f;
        if (ws_next) {
#pragma unroll
            for (int r = 0; r < 8; ++r) wr[r] = ws_next[r * 64 + lane];
        }
#pragma unroll
        for (int i = 0; i < 2; ++i) {
            int node = base + 2 * w + i;
            float d = acc[i] + b2c;
            float mean = wsum(d) * (1.0f / 64.0f);
            float dd = d - mean;
            float var = wsum(dd * dd) * (1.0f / 64.0f);
            float hv = h_in[(size_t)node * HIDD + lane] + dd * rsqrtf(var + 1e-5f) * gc + bbc;
            h_out[(size_t)node * HIDD + lane] = hv;
            if (ws_next) {
                float s0 = wsum(hv * wr[0]), s1 = wsum(hv * wr[1]);
                float s2 = wsum(hv * wr[2]), s3 = wsum(hv * wr[3]);
                float s4 = wsum(hv * wr[4]), s5 = wsum(hv * wr[5]);
                float s6 = wsum(hv * wr[6]), s7 = wsum(hv * wr[7]);
                if (lane == 0) {
                    ((float4*)a_s_out)[node] = make_float4(s0, s1, s2, s3);
                    ((float4*)a_d_out)[node] = make_float4(s4, s5, s6, s7);
                }
            }
        }
    }
}

extern "C" void kernel_launch(void* const* d_in, const int* in_sizes, int n_in,
                              void* d_out, int out_size, void* d_ws, size_t ws_size,
                              hipStream_t stream) {
    const float* x       = (const float*)d_in[0];
    const int*   ei      = (const int*)d_in[1];
    const float* We      = (const float*)d_in[2];
    const float* be      = (const float*)d_in[3];
    const float* Wc      = (const float*)d_in[4];
    const float* att_src = (const float*)d_in[5];
    const float* att_dst = (const float*)d_in[6];
    const float* bc      = (const float*)d_in[7];
    const float* W1      = (const float*)d_in[8];
    const float* b1      = (const float*)d_in[9];
    const float* W2      = (const float*)d_in[10];
    const float* b2      = (const float*)d_in[11];
    const float* ln_g    = (const float*)d_in[12];
    const float* ln_b    = (const float*)d_in[13];

    char* ws = (char*)d_ws;
    size_t off = 0;
    auto alloc = [&](size_t bytes) -> void* {
        void* p = ws + off; off += (bytes + 255) & ~(size_t)255; return p;
    };
    float* h0      = (float*)alloc((size_t)NN * HIDD * 4);
    float* h1      = (float*)alloc((size_t)NN * HIDD * 4);
    float* as0     = (float*)alloc((size_t)NN * NH * 4);
    float* ad0     = (float*)alloc((size_t)NN * NH * 4);
    float* as1     = (float*)alloc((size_t)NN * NH * 4);
    float* ad1     = (float*)alloc((size_t)NN * NH * 4);
    float* ws_all  = (float*)alloc((size_t)NL * 8 * 64 * 4);
    float* W1eff   = (float*)alloc((size_t)NL * HC * DFFD * 4);
    float* b1eff   = (float*)alloc((size_t)NL * DFFD * 4);
    int*   deg     = (int*)alloc((size_t)NN * 4);
    int*   rowptr  = (int*)alloc((size_t)(NN + 1) * 4);
    int*   cursor  = (int*)alloc((size_t)NN * 4);
    int*   csr_src = (int*)alloc((size_t)(NE + NN) * 4);
    (void)ws_size; (void)in_sizes; (void)n_in; (void)out_size;

    ws_kernel<<<8, 256, 0, stream>>>(Wc, att_src, att_dst, ws_all);
    w1eff_kernel<<<NL * 256, 128, 0, stream>>>(Wc, W1, W1eff);
    b1eff_kernel<<<NL, 128, 0, stream>>>(bc, W1, b1, b1eff);
    init_deg<<<(NN + 255) / 256, 256, 0, stream>>>(deg, cursor);
    embed_kernel<<<NN / 16, 256, 0, stream>>>(x, We, be, ws_all, h0, as0, ad0);
    count_edges<<<(NE + 255) / 256, 256, 0, stream>>>(ei, deg);
    scan_kernel<<<1, 1024, 0, stream>>>(deg, rowptr);
    scatter_edges<<<(NE + NN + 255) / 256, 256, 0, stream>>>(ei, rowptr, cursor, csr_src);

    for (int l = 0; l < NL; ++l) {
        const float* hi  = (l & 1) ? h1  : h0;
        const float* asi = (l & 1) ? as1 : as0;
        const float* adi = (l & 1) ? ad1 : ad0;
        float* ho  = (l == NL - 1) ? (float*)d_out : ((l & 1) ? h0 : h1);
        float* aso = (l & 1) ? as0 : as1;
        float* ado = (l & 1) ? ad0 : ad1;
        layer_kernel<<<NN / NPB, 256, 0, stream>>>(hi, asi, adi, rowptr, csr_src,
            W1eff + (size_t)l * HC * DFFD, b1eff + (size_t)l * DFFD,
            W2 + (size_t)l * DFFD * HIDD, b2 + (size_t)l * HIDD,
            ln_g + (size_t)l * HIDD, ln_b + (size_t)l * HIDD,
            (l + 1 < NL) ? (ws_all + (size_t)(l + 1) * 8 * 64) : (const float*)nullptr,
            ho, aso, ado);
    }
}

// Round 14
// 505.025 us; speedup vs baseline: 1.0552x; 1.0552x over previous
//
#include <hip/hip_runtime.h>
#include <cmath>

#define NN   20000   // nodes
#define NE   320000  // edges (before self-loops)
#define IND  256
#define HIDD 64
#define NH   4
#define CD   64
#define HC   256     // NH*CD
#define DFFD 128
#define NL   4
#define NPB  16      // nodes per layer block (R11 optimum)

// All float tensors are float32 (verified R1 vs R2). Output f32.
// R7 lesson: profiled dispatch dur inflated vs wall; trust totals.
// R10+R12 law: kernel needs >=64 VGPRs; never let launch_bounds squeeze below -> spill.
// R12/R13 lesson: NPB=8 loses (2x W1eff staging+barriers); NPB=16 is the optimum.
// R13 theory: phase-1 per-node chains are serial; pair-pipelining adds MLP for free.

static __device__ __forceinline__ float lrelu(float v) { return v > 0.f ? v : 0.2f * v; }
static __device__ __forceinline__ float wsum(float v) { for (int k = 32; k; k >>= 1) v += __shfl_xor(v, k); return v; }
static __device__ __forceinline__ float wmax(float v) { for (int k = 32; k; k >>= 1) v = fmaxf(v, __shfl_xor(v, k)); return v; }
static __device__ __forceinline__ void fma4(float4& a, const float4& v, float s) {
    a.x += v.x * s; a.y += v.y * s; a.z += v.z * s; a.w += v.w * s;
}
static __device__ __forceinline__ void bf4(float4& a) {   // butterfly over lanes 16,32
#pragma unroll
    for (int m = 16; m <= 32; m <<= 1) {
        a.x += __shfl_xor(a.x, m); a.y += __shfl_xor(a.y, m);
        a.z += __shfl_xor(a.z, m); a.w += __shfl_xor(a.w, m);
    }
}

// ---- ws_all[l][r][k]: r=0..3 -> Wc_head@att_src, r=4..7 -> Wc_head@att_dst ----
__global__ void ws_kernel(const float* __restrict__ Wc, const float* __restrict__ att_src,
                          const float* __restrict__ att_dst, float* __restrict__ ws_all) {
    int idx = blockIdx.x * 256 + threadIdx.x;   // 0..2047 = L*8*64
    int l = idx >> 9, r = (idx >> 6) & 7, k = idx & 63;
    int hh = r & 3;
    const float* att = ((r & 4) ? att_dst : att_src) + (size_t)l * NH * CD + hh * CD;
    const float* wrow = Wc + (size_t)l * HIDD * HC + (size_t)k * HC + hh * CD;
    float s = 0.f;
    for (int c = 0; c < CD; ++c) s += wrow[c] * att[c];
    ws_all[idx] = s;
}

// ---- W1eff[l][h*64+k][f] = sum_c Wc[l][k][h*64+c] * W1[l][h*64+c][f] ----
__global__ void w1eff_kernel(const float* __restrict__ Wc, const float* __restrict__ W1,
                             float* __restrict__ W1eff) {
    const int b = blockIdx.x;               // 0..NL*256-1
    const int l = b >> 8, hk = b & 255, hh = hk >> 6, kl = hk & 63;
    const int f = threadIdx.x;              // 0..127
    const float* wc = Wc + (size_t)l * HIDD * HC + (size_t)kl * HC + hh * 64;
    const float* w1 = W1 + (size_t)l * HC * DFFD + (size_t)(hh * 64) * DFFD + f;
    float s = 0.f;
#pragma unroll 4
    for (int c = 0; c < 64; ++c) s += wc[c] * w1[(size_t)c * DFFD];
    W1eff[(size_t)l * HC * DFFD + (size_t)hk * DFFD + f] = s;
}

// ---- b1eff[l][f] = b1[l][f] + sum_c bc[l][c] * W1[l][c][f] ----
__global__ void b1eff_kernel(const float* __restrict__ bc, const float* __restrict__ W1,
                             const float* __restrict__ b1, float* __restrict__ b1eff) {
    const int l = blockIdx.x, f = threadIdx.x;   // NL blocks x 128 threads
    const float* w1 = W1 + (size_t)l * HC * DFFD + f;
    const float* bcl = bc + (size_t)l * HC;
    float s = b1[(size_t)l * DFFD + f];
    for (int c = 0; c < HC; ++c) s += bcl[c] * w1[(size_t)c * DFFD];
    b1eff[l * DFFD + f] = s;
}

// ---- embed: h = (x @ We + be) * 8, fused layer-0 attention dots; 16 nodes/block ----
__global__ __launch_bounds__(256) void embed_kernel(const float* __restrict__ x,
                                                    const float* __restrict__ We,
                                                    const float* __restrict__ be,
                                                    const float* __restrict__ ws_all,
                                                    float* __restrict__ h,
                                                    float* __restrict__ a_s, float* __restrict__ a_d) {
    __shared__ float s_x[16 * IND];   // 16KB
    const int base = blockIdx.x * 16, t = threadIdx.x;
    for (int idx = t; idx < 16 * IND / 4; idx += 256)
        ((float4*)s_x)[idx] = ((const float4*)(x + (size_t)base * IND))[idx];
    __syncthreads();
    const int c = t & 63, g = t >> 6;   // wave g: nodes 4g..4g+3, lane = channel c
    float acc[4] = {0.f, 0.f, 0.f, 0.f};
    const float4* sx4 = (const float4*)s_x;
#pragma unroll 2
    for (int k4 = 0; k4 < IND / 4; ++k4) {
        float w0 = We[(4 * k4 + 0) * HIDD + c];
        float w1 = We[(4 * k4 + 1) * HIDD + c];
        float w2 = We[(4 * k4 + 2) * HIDD + c];
        float w3 = We[(4 * k4 + 3) * HIDD + c];
#pragma unroll
        for (int i = 0; i < 4; ++i) {
            float4 v = sx4[(4 * g + i) * (IND / 4) + k4];
            acc[i] += v.x * w0 + v.y * w1 + v.z * w2 + v.w * w3;
        }
    }
    float bias = be[c];
    float wr[8];
#pragma unroll
    for (int r = 0; r < 8; ++r) wr[r] = ws_all[r * 64 + c];   // layer 0
#pragma unroll
    for (int i = 0; i < 4; ++i) {
        int node = base + 4 * g + i;
        float hv = (acc[i] + bias) * 8.0f;
        h[(size_t)node * HIDD + c] = hv;
        float s0 = wsum(hv * wr[0]), s1 = wsum(hv * wr[1]);
        float s2 = wsum(hv * wr[2]), s3 = wsum(hv * wr[3]);
        float s4 = wsum(hv * wr[4]), s5 = wsum(hv * wr[5]);
        float s6 = wsum(hv * wr[6]), s7 = wsum(hv * wr[7]);
        if (c == 0) {
            ((float4*)a_s)[node] = make_float4(s0, s1, s2, s3);
            ((float4*)a_d)[node] = make_float4(s4, s5, s6, s7);
        }
    }
}

// ---------------- CSR build ----------------
__global__ void init_deg(int* __restrict__ deg, int* __restrict__ cursor) {
    int i = blockIdx.x * blockDim.x + threadIdx.x;
    if (i < NN) { deg[i] = 1; cursor[i] = 0; }   // self-loop
}

__global__ void count_edges(const int* __restrict__ ei, int* __restrict__ deg) {
    int e = blockIdx.x * blockDim.x + threadIdx.x;
    if (e < NE) atomicAdd(&deg[ei[NE + e]], 1);
}

__global__ void scan_kernel(const int* __restrict__ deg, int* __restrict__ rowptr) {
    __shared__ int part[1024];
    const int t = threadIdx.x;
    const int CH = (NN + 1023) / 1024;
    int lo = t * CH, hi = lo + CH; if (hi > NN) hi = NN;
    int s = 0;
    for (int i = lo; i < hi; ++i) s += deg[i];
    part[t] = s;
    __syncthreads();
    for (int off = 1; off < 1024; off <<= 1) {
        int v = 0;
        if (t >= off) v = part[t - off];
        __syncthreads();
        if (t >= off) part[t] += v;
        __syncthreads();
    }
    int base = (t == 0) ? 0 : part[t - 1];
    for (int i = lo; i < hi; ++i) { rowptr[i] = base; base += deg[i]; }
    if (lo <= NN - 1 && NN - 1 < hi) rowptr[NN] = base;
}

__global__ void scatter_edges(const int* __restrict__ ei, const int* __restrict__ rowptr,
                              int* __restrict__ cursor, int* __restrict__ csr_src) {
    int e = blockIdx.x * blockDim.x + threadIdx.x;
    if (e < NE) {
        int s = ei[e], d = ei[NE + e];
        int pos = atomicAdd(&cursor[d], 1);
        csr_src[rowptr[d] + pos] = s;
    } else if (e < NE + NN) {
        int i = e - NE;
        int pos = atomicAdd(&cursor[i], 1);
        csr_src[rowptr[i] + pos] = i;
    }
}

// ---- fused layer: pair-pipelined gather/softmax-aggregate -> GEMM1 -> GEMM2+LN+res ----
// 16 nodes/block, 1250 blocks. LDS: s_in 16KB + s_buf 16KB = 32KB.
// __launch_bounds__(256,4): VGPR budget 128 >= natural ~90 (no spill).
__global__ __launch_bounds__(256, 4) void layer_kernel(
    const float* __restrict__ h_in, const float* __restrict__ a_s_in, const float* __restrict__ a_d_in,
    const int* __restrict__ rowptr, const int* __restrict__ csr_src,
    const float* __restrict__ W1eff, const float* __restrict__ b1eff,
    const float* __restrict__ W2, const float* __restrict__ b2,
    const float* __restrict__ ln_g, const float* __restrict__ ln_b,
    const float* __restrict__ ws_next,
    float* __restrict__ h_out, float* __restrict__ a_s_out, float* __restrict__ a_d_out) {
    __shared__ float s_in[NPB * HC];  // 16KB aggregated node vectors
    __shared__ float s_buf[4096];     // 16KB: gather scratch (10KB) -> W1eff k-tile -> mid
    const int base = blockIdx.x * NPB, t = threadIdx.x, wave = t >> 6, lane = t & 63;

    // ---- phase 1: softmax aggregation, PAIR-pipelined: 4 nodes/wave as 2 pairs ----
    // lane = (eg = lane>>4, cg = lane&15); b128 load covers 4 edges x 4 channels.
    {
        int*    s_src = (int*)s_buf + wave * 128;             // per-wave [2][64] (2KB total)
        float4* s_w   = (float4*)(s_buf + 512) + wave * 128;  // per-wave [2][64] (8KB total)
        const float4* as4 = (const float4*)a_s_in;
        const float4* h4  = (const float4*)h_in;
        const int eg = lane >> 4, cg = lane & 15;
        float4* si4 = (float4*)s_in;

        for (int pp = 0; pp < 2; ++pp) {
            const int node0 = base + wave * 4 + pp * 2, node1 = node0 + 1;
            const int lo0 = rowptr[node0], n0 = rowptr[node0 + 1] - lo0;
            const int lo1 = rowptr[node1], n1 = rowptr[node1 + 1] - lo1;

            if (n0 <= 64 && n1 <= 64) {
                // --- fused fast path: both nodes' chains overlapped ---
                const float4 ad0 = ((const float4*)a_d_in)[node0];
                const float4 ad1 = ((const float4*)a_d_in)[node1];
                int src0 = 0, src1 = 0;
                if (lane < n0) src0 = csr_src[lo0 + lane];
                if (lane < n1) src1 = csr_src[lo1 + lane];   // both loads in flight
                float e0 = -1e30f, e1 = -1e30f, e2 = -1e30f, e3 = -1e30f;
                float f0 = -1e30f, f1 = -1e30f, f2 = -1e30f, f3 = -1e30f;
                if (lane < n0) {
                    s_src[lane] = src0;
                    float4 a = as4[src0];
                    e0 = lrelu(a.x + ad0.x); e1 = lrelu(a.y + ad0.y);
                    e2 = lrelu(a.z + ad0.z); e3 = lrelu(a.w + ad0.w);
                }
                if (lane < n1) {
                    s_src[64 + lane] = src1;
                    float4 a = as4[src1];
                    f0 = lrelu(a.x + ad1.x); f1 = lrelu(a.y + ad1.y);
                    f2 = lrelu(a.z + ad1.z); f3 = lrelu(a.w + ad1.w);
                }
                float M0 = wmax(e0), M1 = wmax(e1), M2 = wmax(e2), M3 = wmax(e3);
                float N0 = wmax(f0), N1 = wmax(f1), N2 = wmax(f2), N3 = wmax(f3);
                float p0 = __expf(e0 - M0), p1 = __expf(e1 - M1);
                float p2 = __expf(e2 - M2), p3 = __expf(e3 - M3);
                float q0 = __expf(f0 - N0), q1 = __expf(f1 - N1);
                float q2 = __expf(f2 - N2), q3 = __expf(f3 - N3);
                float iz0 = 1.f / (wsum(p0) + 1e-16f), iz1 = 1.f / (wsum(p1) + 1e-16f);
                float iz2 = 1.f / (wsum(p2) + 1e-16f), iz3 = 1.f / (wsum(p3) + 1e-16f);
                float jz0 = 1.f / (wsum(q0) + 1e-16f), jz1 = 1.f / (wsum(q1) + 1e-16f);
                float jz2 = 1.f / (wsum(q2) + 1e-16f), jz3 = 1.f / (wsum(q3) + 1e-16f);
                if (lane < n0) s_w[lane]      = make_float4(p0 * iz0, p1 * iz1, p2 * iz2, p3 * iz3);
                if (lane < n1) s_w[64 + lane] = make_float4(q0 * jz0, q1 * jz1, q2 * jz2, q3 * jz3);
                const int n0_8 = (n0 + 7) & ~7, n1_8 = (n1 + 7) & ~7;
                if (lane >= n0 && lane < n0_8) { s_src[lane] = s_src[0]; s_w[lane] = make_float4(0.f, 0.f, 0.f, 0.f); }
                if (lane >= n1 && lane < n1_8) { s_src[64 + lane] = s_src[64]; s_w[64 + lane] = make_float4(0.f, 0.f, 0.f, 0.f); }

                float4 A0 = make_float4(0.f, 0.f, 0.f, 0.f), A1 = A0, A2 = A0, A3 = A0;
                float4 B0 = A0, B1 = A0, B2 = A0, B3 = A0;
                const int jmax = (n0_8 > n1_8) ? n0_8 : n1_8;
                for (int j = 0; j < jmax; j += 8) {   // interleaved: up to 4 b128 in flight
                    if (j < n0_8) {
                        int sA = s_src[j + eg], sB = s_src[j + 4 + eg];
                        float4 vA = h4[(size_t)sA * 16 + cg];
                        float4 vB = h4[(size_t)sB * 16 + cg];
                        float4 wA = s_w[j + eg], wB = s_w[j + 4 + eg];
                        fma4(A0, vA, wA.x); fma4(A1, vA, wA.y); fma4(A2, vA, wA.z); fma4(A3, vA, wA.w);
                        fma4(A0, vB, wB.x); fma4(A1, vB, wB.y); fma4(A2, vB, wB.z); fma4(A3, vB, wB.w);
                    }
                    if (j < n1_8) {
                        int sC = s_src[64 + j + eg], sD = s_src[64 + j + 4 + eg];
                        float4 vC = h4[(size_t)sC * 16 + cg];
                        float4 vD = h4[(size_t)sD * 16 + cg];
                        float4 wC = s_w[64 + j + eg], wD = s_w[64 + j + 4 + eg];
                        fma4(B0, vC, wC.x); fma4(B1, vC, wC.y); fma4(B2, vC, wC.z); fma4(B3, vC, wC.w);
                        fma4(B0, vD, wD.x); fma4(B1, vD, wD.y); fma4(B2, vD, wD.z); fma4(B3, vD, wD.w);
                    }
                }
                bf4(A0); bf4(A1); bf4(A2); bf4(A3);
                bf4(B0); bf4(B1); bf4(B2); bf4(B3);
                const int r0 = wave * 4 + pp * 2;
                float4 outA = (eg == 0) ? A0 : (eg == 1) ? A1 : (eg == 2) ? A2 : A3;
                float4 outB = (eg == 0) ? B0 : (eg == 1) ? B1 : (eg == 2) ? B2 : B3;
                si4[r0 * 64 + lane] = outA;
                si4[(r0 + 1) * 64 + lane] = outB;
            } else {
                // --- fallback: sequential per-node (deg > 64 is rare) ---
                for (int nd = 0; nd < 2; ++nd) {
                    const int node = node0 + nd;
                    const int lo = (nd == 0) ? lo0 : lo1;
                    const int n  = (nd == 0) ? n0  : n1;
                    const float4 ad = ((const float4*)a_d_in)[node];
                    float4 a0 = make_float4(0.f, 0.f, 0.f, 0.f);
                    float4 a1 = a0, a2 = a0, a3 = a0;
                    if (n <= 64) {
                        float e0 = -1e30f, e1 = -1e30f, e2 = -1e30f, e3 = -1e30f;
                        if (lane < n) {
                            int s = csr_src[lo + lane];
                            s_src[lane] = s;
                            float4 a = as4[s];
                            e0 = lrelu(a.x + ad.x); e1 = lrelu(a.y + ad.y);
                            e2 = lrelu(a.z + ad.z); e3 = lrelu(a.w + ad.w);
                        }
                        float M0 = wmax(e0), M1 = wmax(e1), M2 = wmax(e2), M3 = wmax(e3);
                        float p0 = __expf(e0 - M0), p1 = __expf(e1 - M1);
                        float p2 = __expf(e2 - M2), p3 = __expf(e3 - M3);
                        float iz0 = 1.f / (wsum(p0) + 1e-16f), iz1 = 1.f / (wsum(p1) + 1e-16f);
                        float iz2 = 1.f / (wsum(p2) + 1e-16f), iz3 = 1.f / (wsum(p3) + 1e-16f);
                        if (lane < n) s_w[lane] = make_float4(p0 * iz0, p1 * iz1, p2 * iz2, p3 * iz3);
                        const int n8 = (n + 7) & ~7;
                        if (lane >= n && lane < n8) { s_src[lane] = s_src[0]; s_w[lane] = make_float4(0.f, 0.f, 0.f, 0.f); }
                        for (int j = 0; j < n8; j += 8) {
                            int sA = s_src[j + eg], sB = s_src[j + 4 + eg];
                            float4 vA = h4[(size_t)sA * 16 + cg];
                            float4 vB = h4[(size_t)sB * 16 + cg];
                            float4 wA = s_w[j + eg], wB = s_w[j + 4 + eg];
                            fma4(a0, vA, wA.x); fma4(a1, vA, wA.y); fma4(a2, vA, wA.z); fma4(a3, vA, wA.w);
                            fma4(a0, vB, wB.x); fma4(a1, vB, wB.y); fma4(a2, vB, wB.z); fma4(a3, vB, wB.w);
                        }
                    } else {
                        float m0 = -1e30f, m1 = -1e30f, m2 = -1e30f, m3 = -1e30f;
                        for (int j = lane; j < n; j += 64) {
                            int s = csr_src[lo + j];
                            float4 a = as4[s];
                            m0 = fmaxf(m0, lrelu(a.x + ad.x)); m1 = fmaxf(m1, lrelu(a.y + ad.y));
                            m2 = fmaxf(m2, lrelu(a.z + ad.z)); m3 = fmaxf(m3, lrelu(a.w + ad.w));
                        }
                        m0 = wmax(m0); m1 = wmax(m1); m2 = wmax(m2); m3 = wmax(m3);
                        float z0 = 0.f, z1 = 0.f, z2 = 0.f, z3 = 0.f;
                        for (int j = lane; j < n; j += 64) {
                            int s = csr_src[lo + j];
                            float4 a = as4[s];
                            z0 += __expf(lrelu(a.x + ad.x) - m0); z1 += __expf(lrelu(a.y + ad.y) - m1);
                            z2 += __expf(lrelu(a.z + ad.z) - m2); z3 += __expf(lrelu(a.w + ad.w) - m3);
                        }
                        float iz0 = 1.f / (wsum(z0) + 1e-16f), iz1 = 1.f / (wsum(z1) + 1e-16f);
                        float iz2 = 1.f / (wsum(z2) + 1e-16f), iz3 = 1.f / (wsum(z3) + 1e-16f);
                        for (int cb = 0; cb < n; cb += 64) {
                            int nn = n - cb; if (nn > 64) nn = 64;
                            if (lane < nn) {
                                int s = csr_src[lo + cb + lane];
                                s_src[lane] = s;
                                float4 a = as4[s];
                                s_w[lane] = make_float4(__expf(lrelu(a.x + ad.x) - m0) * iz0,
                                                        __expf(lrelu(a.y + ad.y) - m1) * iz1,
                                                        __expf(lrelu(a.z + ad.z) - m2) * iz2,
                                                        __expf(lrelu(a.w + ad.w) - m3) * iz3);
                            }
                            const int nn8 = (nn + 7) & ~7;
                            if (lane >= nn && lane < nn8) { s_src[lane] = s_src[0]; s_w[lane] = make_float4(0.f, 0.f, 0.f, 0.f); }
                            for (int j = 0; j < nn8; j += 8) {
                                int sA = s_src[j + eg], sB = s_src[j + 4 + eg];
                                float4 vA = h4[(size_t)sA * 16 + cg];
                                float4 vB = h4[(size_t)sB * 16 + cg];
                                float4 wA = s_w[j + eg], wB = s_w[j + 4 + eg];
                                fma4(a0, vA, wA.x); fma4(a1, vA, wA.y); fma4(a2, vA, wA.z); fma4(a3, vA, wA.w);
                                fma4(a0, vB, wB.x); fma4(a1, vB, wB.y); fma4(a2, vB, wB.z); fma4(a3, vB, wB.w);
                            }
                        }
                    }
                    bf4(a0); bf4(a1); bf4(a2); bf4(a3);
                    const int r = wave * 4 + pp * 2 + nd;
                    float4 outv = (eg == 0) ? a0 : (eg == 1) ? a1 : (eg == 2) ? a2 : a3;
                    si4[r * 64 + lane] = outv;
                }
            }
        }
    }
    __syncthreads();

    // ---- phase 2: GEMM1 mid = gelu(s_in @ W1eff + b1eff); 2 nodes x 4 f per thread;
    //      W1eff staged in 8 LDS k-tiles of 32x128 (16KB each) ----
    const int fg = t & 31, ng2 = t >> 5;   // f = 4*fg.., nodes 2*ng2..2*ng2+1
    float4 acc1[2];
    acc1[0] = make_float4(0.f, 0.f, 0.f, 0.f);
    acc1[1] = make_float4(0.f, 0.f, 0.f, 0.f);
    {
        const float4* si4 = (const float4*)s_in;
        float4* sB4 = (float4*)s_buf;
        for (int kt = 0; kt < 8; ++kt) {
            __syncthreads();   // prior s_buf readers done (kt=0: gather scratch)
            const float4* gsrc = (const float4*)(W1eff + (size_t)kt * 32 * DFFD);
            for (int idx = t; idx < 1024; idx += 256) sB4[idx] = gsrc[idx];
            __syncthreads();
#pragma unroll
            for (int k4 = 0; k4 < 8; ++k4) {
                float4 w0 = sB4[(4 * k4 + 0) * 32 + fg];   // W1eff[k][4fg..4fg+3]
                float4 w1 = sB4[(4 * k4 + 1) * 32 + fg];
                float4 w2 = sB4[(4 * k4 + 2) * 32 + fg];
                float4 w3 = sB4[(4 * k4 + 3) * 32 + fg];
#pragma unroll
                for (int i = 0; i < 2; ++i) {
                    float4 v = si4[(2 * ng2 + i) * 64 + kt * 8 + k4];   // half-wave uniform
                    acc1[i].x += v.x * w0.x + v.y * w1.x + v.z * w2.x + v.w * w3.x;
                    acc1[i].y += v.x * w0.y + v.y * w1.y + v.z * w2.y + v.w * w3.y;
                    acc1[i].z += v.x * w0.z + v.y * w1.z + v.z * w2.z + v.w * w3.z;
                    acc1[i].w += v.x * w0.w + v.y * w1.w + v.z * w2.w + v.w * w3.w;
                }
            }
        }
    }
    __syncthreads();   // last tile consumed; s_buf becomes mid
    {
        float4 bb = *(const float4*)(b1eff + 4 * fg);
#pragma unroll
        for (int i = 0; i < 2; ++i) {
            float dx = acc1[i].x + bb.x, dy = acc1[i].y + bb.y;
            float dz = acc1[i].z + bb.z, dw = acc1[i].w + bb.w;
            ((float4*)s_buf)[(2 * ng2 + i) * 32 + fg] = make_float4(
                0.5f * dx * (1.f + erff(dx * 0.70710678118654752f)),
                0.5f * dy * (1.f + erff(dy * 0.70710678118654752f)),
                0.5f * dz * (1.f + erff(dz * 0.70710678118654752f)),
                0.5f * dw * (1.f + erff(dw * 0.70710678118654752f)));
        }
    }
    __syncthreads();

    // ---- phase 3: GEMM2 + LN + residual + next-layer attdots; 4 nodes/wave ----
    {
        const int w = t >> 6;   // wave w -> nodes 4w..4w+3, lane = channel
        float acc[4];
#pragma unroll
        for (int i = 0; i < 4; ++i) acc[i] = 0.f;
        const float4* sm4 = (const float4*)s_buf;
#pragma unroll 4
        for (int k4 = 0; k4 < 32; ++k4) {
            float w0 = W2[(4 * k4 + 0) * HIDD + lane];
            float w1 = W2[(4 * k4 + 1) * HIDD + lane];
            float w2 = W2[(4 * k4 + 2) * HIDD + lane];
            float w3 = W2[(4 * k4 + 3) * HIDD + lane];
#pragma unroll
            for (int i = 0; i < 4; ++i) {
                float4 v = sm4[(4 * w + i) * 32 + k4];   // wave-uniform broadcast
                acc[i] += v.x * w0 + v.y * w1 + v.z * w2 + v.w * w3;
            }
        }
        const float b2c = b2[lane], gc = ln_g[lane], bbc = ln_b[lane];
        float wr[8];
#pragma unroll
        for (int r = 0; r < 8; ++r) wr[r] = 0.f;
        if (ws_next) {
#pragma unroll
            for (int r = 0; r < 8; ++r) wr[r] = ws_next[r * 64 + lane];
        }
#pragma unroll
        for (int i = 0; i < 4; ++i) {
            int node = base + 4 * w + i;
            float d = acc[i] + b2c;
            float mean = wsum(d) * (1.0f / 64.0f);
            float dd = d - mean;
            float var = wsum(dd * dd) * (1.0f / 64.0f);
            float hv = h_in[(size_t)node * HIDD + lane] + dd * rsqrtf(var + 1e-5f) * gc + bbc;
            h_out[(size_t)node * HIDD + lane] = hv;
            if (ws_next) {
                float s0 = wsum(hv * wr[0]), s1 = wsum(hv * wr[1]);
                float s2 = wsum(hv * wr[2]), s3 = wsum(hv * wr[3]);
                float s4 = wsum(hv * wr[4]), s5 = wsum(hv * wr[5]);
                float s6 = wsum(hv * wr[6]), s7 = wsum(hv * wr[7]);
                if (lane == 0) {
                    ((float4*)a_s_out)[node] = make_float4(s0, s1, s2, s3);
                    ((float4*)a_d_out)[node] = make_float4(s4, s5, s6, s7);
                }
            }
        }
    }
}

extern "C" void kernel_launch(void* const* d_in, const int* in_sizes, int n_in,
                              void* d_out, int out_size, void* d_ws, size_t ws_size,
                              hipStream_t stream) {
    const float* x       = (const float*)d_in[0];
    const int*   ei      = (const int*)d_in[1];
    const float* We      = (const float*)d_in[2];
    const float* be      = (const float*)d_in[3];
    const float* Wc      = (const float*)d_in[4];
    const float* att_src = (const float*)d_in[5];
    const float* att_dst = (const float*)d_in[6];
    const float* bc      = (const float*)d_in[7];
    const float* W1      = (const float*)d_in[8];
    const float* b1      = (const float*)d_in[9];
    const float* W2      = (const float*)d_in[10];
    const float* b2      = (const float*)d_in[11];
    const float* ln_g    = (const float*)d_in[12];
    const float* ln_b    = (const float*)d_in[13];

    char* ws = (char*)d_ws;
    size_t off = 0;
    auto alloc = [&](size_t bytes) -> void* {
        void* p = ws + off; off += (bytes + 255) & ~(size_t)255; return p;
    };
    float* h0      = (float*)alloc((size_t)NN * HIDD * 4);
    float* h1      = (float*)alloc((size_t)NN * HIDD * 4);
    float* as0     = (float*)alloc((size_t)NN * NH * 4);
    float* ad0     = (float*)alloc((size_t)NN * NH * 4);
    float* as1     = (float*)alloc((size_t)NN * NH * 4);
    float* ad1     = (float*)alloc((size_t)NN * NH * 4);
    float* ws_all  = (float*)alloc((size_t)NL * 8 * 64 * 4);
    float* W1eff   = (float*)alloc((size_t)NL * HC * DFFD * 4);
    float* b1eff   = (float*)alloc((size_t)NL * DFFD * 4);
    int*   deg     = (int*)alloc((size_t)NN * 4);
    int*   rowptr  = (int*)alloc((size_t)(NN + 1) * 4);
    int*   cursor  = (int*)alloc((size_t)NN * 4);
    int*   csr_src = (int*)alloc((size_t)(NE + NN) * 4);
    (void)ws_size; (void)in_sizes; (void)n_in; (void)out_size;

    ws_kernel<<<8, 256, 0, stream>>>(Wc, att_src, att_dst, ws_all);
    w1eff_kernel<<<NL * 256, 128, 0, stream>>>(Wc, W1, W1eff);
    b1eff_kernel<<<NL, 128, 0, stream>>>(bc, W1, b1, b1eff);
    init_deg<<<(NN + 255) / 256, 256, 0, stream>>>(deg, cursor);
    embed_kernel<<<NN / 16, 256, 0, stream>>>(x, We, be, ws_all, h0, as0, ad0);
    count_edges<<<(NE + 255) / 256, 256, 0, stream>>>(ei, deg);
    scan_kernel<<<1, 1024, 0, stream>>>(deg, rowptr);
    scatter_edges<<<(NE + NN + 255) / 256, 256, 0, stream>>>(ei, rowptr, cursor, csr_src);

    for (int l = 0; l < NL; ++l) {
        const float* hi  = (l & 1) ? h1  : h0;
        const float* asi = (l & 1) ? as1 : as0;
        const float* adi = (l & 1) ? ad1 : ad0;
        float* ho  = (l == NL - 1) ? (float*)d_out : ((l & 1) ? h0 : h1);
        float* aso = (l & 1) ? as0 : as1;
        float* ado = (l & 1) ? ad0 : ad1;
        layer_kernel<<<NN / NPB, 256, 0, stream>>>(hi, asi, adi, rowptr, csr_src,
            W1eff + (size_t)l * HC * DFFD, b1eff + (size_t)l * DFFD,
            W2 + (size_t)l * DFFD * HIDD, b2 + (size_t)l * HIDD,
            ln_g + (size_t)l * HIDD, ln_b + (size_t)l * HIDD,
            (l + 1 < NL) ? (ws_all + (size_t)(l + 1) * 8 * 64) : (const float*)nullptr,
            ho, aso, ado);
    }
}

// Round 15
// 479.382 us; speedup vs baseline: 1.1116x; 1.0535x over previous
//
#include <hip/hip_runtime.h>
#include <cmath>

#define NN   20000   // nodes
#define NE   320000  // edges (before self-loops)
#define IND  256
#define HIDD 64
#define NH   4
#define CD   64
#define HC   256     // NH*CD
#define DFFD 128
#define NL   4
#define NPB  16      // nodes per layer block (R11 optimum)

// All float tensors are float32 (verified R1 vs R2). Output f32.
// R7 lesson: profiled dispatch dur inflated vs wall; trust totals.
// R10+R12 law: kernel needs >=64 VGPRs free; never let launch_bounds squeeze -> spill.
// R12/R13 lesson: NPB=8 loses (2x W1eff staging+barriers); NPB=16 optimum.
// R14 lesson: pair-pipelining phase 1 doubles live state -> spill; sequential wins.
// R15: double-buffer W1eff tiles so the tile-stage barrier finds data resident.

static __device__ __forceinline__ float lrelu(float v) { return v > 0.f ? v : 0.2f * v; }
static __device__ __forceinline__ float wsum(float v) { for (int k = 32; k; k >>= 1) v += __shfl_xor(v, k); return v; }
static __device__ __forceinline__ float wmax(float v) { for (int k = 32; k; k >>= 1) v = fmaxf(v, __shfl_xor(v, k)); return v; }
static __device__ __forceinline__ void fma4(float4& a, const float4& v, float s) {
    a.x += v.x * s; a.y += v.y * s; a.z += v.z * s; a.w += v.w * s;
}

// ---- ws_all[l][r][k]: r=0..3 -> Wc_head@att_src, r=4..7 -> Wc_head@att_dst ----
__global__ void ws_kernel(const float* __restrict__ Wc, const float* __restrict__ att_src,
                          const float* __restrict__ att_dst, float* __restrict__ ws_all) {
    int idx = blockIdx.x * 256 + threadIdx.x;   // 0..2047 = L*8*64
    int l = idx >> 9, r = (idx >> 6) & 7, k = idx & 63;
    int hh = r & 3;
    const float* att = ((r & 4) ? att_dst : att_src) + (size_t)l * NH * CD + hh * CD;
    const float* wrow = Wc + (size_t)l * HIDD * HC + (size_t)k * HC + hh * CD;
    float s = 0.f;
    for (int c = 0; c < CD; ++c) s += wrow[c] * att[c];
    ws_all[idx] = s;
}

// ---- W1eff[l][h*64+k][f] = sum_c Wc[l][k][h*64+c] * W1[l][h*64+c][f] ----
__global__ void w1eff_kernel(const float* __restrict__ Wc, const float* __restrict__ W1,
                             float* __restrict__ W1eff) {
    const int b = blockIdx.x;               // 0..NL*256-1
    const int l = b >> 8, hk = b & 255, hh = hk >> 6, kl = hk & 63;
    const int f = threadIdx.x;              // 0..127
    const float* wc = Wc + (size_t)l * HIDD * HC + (size_t)kl * HC + hh * 64;
    const float* w1 = W1 + (size_t)l * HC * DFFD + (size_t)(hh * 64) * DFFD + f;
    float s = 0.f;
#pragma unroll 4
    for (int c = 0; c < 64; ++c) s += wc[c] * w1[(size_t)c * DFFD];
    W1eff[(size_t)l * HC * DFFD + (size_t)hk * DFFD + f] = s;
}

// ---- b1eff[l][f] = b1[l][f] + sum_c bc[l][c] * W1[l][c][f] ----
__global__ void b1eff_kernel(const float* __restrict__ bc, const float* __restrict__ W1,
                             const float* __restrict__ b1, float* __restrict__ b1eff) {
    const int l = blockIdx.x, f = threadIdx.x;   // NL blocks x 128 threads
    const float* w1 = W1 + (size_t)l * HC * DFFD + f;
    const float* bcl = bc + (size_t)l * HC;
    float s = b1[(size_t)l * DFFD + f];
    for (int c = 0; c < HC; ++c) s += bcl[c] * w1[(size_t)c * DFFD];
    b1eff[l * DFFD + f] = s;
}

// ---- embed: h = (x @ We + be) * 8, fused layer-0 attention dots; 16 nodes/block ----
__global__ __launch_bounds__(256) void embed_kernel(const float* __restrict__ x,
                                                    const float* __restrict__ We,
                                                    const float* __restrict__ be,
                                                    const float* __restrict__ ws_all,
                                                    float* __restrict__ h,
                                                    float* __restrict__ a_s, float* __restrict__ a_d) {
    __shared__ float s_x[16 * IND];   // 16KB
    const int base = blockIdx.x * 16, t = threadIdx.x;
    for (int idx = t; idx < 16 * IND / 4; idx += 256)
        ((float4*)s_x)[idx] = ((const float4*)(x + (size_t)base * IND))[idx];
    __syncthreads();
    const int c = t & 63, g = t >> 6;   // wave g: nodes 4g..4g+3, lane = channel c
    float acc[4] = {0.f, 0.f, 0.f, 0.f};
    const float4* sx4 = (const float4*)s_x;
#pragma unroll 2
    for (int k4 = 0; k4 < IND / 4; ++k4) {
        float w0 = We[(4 * k4 + 0) * HIDD + c];
        float w1 = We[(4 * k4 + 1) * HIDD + c];
        float w2 = We[(4 * k4 + 2) * HIDD + c];
        float w3 = We[(4 * k4 + 3) * HIDD + c];
#pragma unroll
        for (int i = 0; i < 4; ++i) {
            float4 v = sx4[(4 * g + i) * (IND / 4) + k4];
            acc[i] += v.x * w0 + v.y * w1 + v.z * w2 + v.w * w3;
        }
    }
    float bias = be[c];
    float wr[8];
#pragma unroll
    for (int r = 0; r < 8; ++r) wr[r] = ws_all[r * 64 + c];   // layer 0
#pragma unroll
    for (int i = 0; i < 4; ++i) {
        int node = base + 4 * g + i;
        float hv = (acc[i] + bias) * 8.0f;
        h[(size_t)node * HIDD + c] = hv;
        float s0 = wsum(hv * wr[0]), s1 = wsum(hv * wr[1]);
        float s2 = wsum(hv * wr[2]), s3 = wsum(hv * wr[3]);
        float s4 = wsum(hv * wr[4]), s5 = wsum(hv * wr[5]);
        float s6 = wsum(hv * wr[6]), s7 = wsum(hv * wr[7]);
        if (c == 0) {
            ((float4*)a_s)[node] = make_float4(s0, s1, s2, s3);
            ((float4*)a_d)[node] = make_float4(s4, s5, s6, s7);
        }
    }
}

// ---------------- CSR build ----------------
__global__ void init_deg(int* __restrict__ deg, int* __restrict__ cursor) {
    int i = blockIdx.x * blockDim.x + threadIdx.x;
    if (i < NN) { deg[i] = 1; cursor[i] = 0; }   // self-loop
}

__global__ void count_edges(const int* __restrict__ ei, int* __restrict__ deg) {
    int e = blockIdx.x * blockDim.x + threadIdx.x;
    if (e < NE) atomicAdd(&deg[ei[NE + e]], 1);
}

__global__ void scan_kernel(const int* __restrict__ deg, int* __restrict__ rowptr) {
    __shared__ int part[1024];
    const int t = threadIdx.x;
    const int CH = (NN + 1023) / 1024;
    int lo = t * CH, hi = lo + CH; if (hi > NN) hi = NN;
    int s = 0;
    for (int i = lo; i < hi; ++i) s += deg[i];
    part[t] = s;
    __syncthreads();
    for (int off = 1; off < 1024; off <<= 1) {
        int v = 0;
        if (t >= off) v = part[t - off];
        __syncthreads();
        if (t >= off) part[t] += v;
        __syncthreads();
    }
    int base = (t == 0) ? 0 : part[t - 1];
    for (int i = lo; i < hi; ++i) { rowptr[i] = base; base += deg[i]; }
    if (lo <= NN - 1 && NN - 1 < hi) rowptr[NN] = base;
}

__global__ void scatter_edges(const int* __restrict__ ei, const int* __restrict__ rowptr,
                              int* __restrict__ cursor, int* __restrict__ csr_src) {
    int e = blockIdx.x * blockDim.x + threadIdx.x;
    if (e < NE) {
        int s = ei[e], d = ei[NE + e];
        int pos = atomicAdd(&cursor[d], 1);
        csr_src[rowptr[d] + pos] = s;
    } else if (e < NE + NN) {
        int i = e - NE;
        int pos = atomicAdd(&cursor[i], 1);
        csr_src[rowptr[i] + pos] = i;
    }
}

// ---- fused layer: gather/softmax-aggregate -> GEMM1 (dbuf W1eff) -> GEMM2+LN+res ----
// 16 nodes/block, 1250 blocks. LDS: s_in 16KB + s_buf 16KB = 32KB.
// __launch_bounds__(256,4): VGPR budget 128 >= natural ~72 (no spill).
__global__ __launch_bounds__(256, 4) void layer_kernel(
    const float* __restrict__ h_in, const float* __restrict__ a_s_in, const float* __restrict__ a_d_in,
    const int* __restrict__ rowptr, const int* __restrict__ csr_src,
    const float* __restrict__ W1eff, const float* __restrict__ b1eff,
    const float* __restrict__ W2, const float* __restrict__ b2,
    const float* __restrict__ ln_g, const float* __restrict__ ln_b,
    const float* __restrict__ ws_next,
    float* __restrict__ h_out, float* __restrict__ a_s_out, float* __restrict__ a_d_out) {
    __shared__ float s_in[NPB * HC];  // 16KB aggregated node vectors
    __shared__ float s_buf[4096];     // 16KB: gather scratch -> dbuf W1eff tiles -> mid
    const int base = blockIdx.x * NPB, t = threadIdx.x, wave = t >> 6, lane = t & 63;

    // ---- phase 1: softmax-attention aggregation, wave-synchronous, 4 nodes/wave ----
    // lane = (eg = lane>>4, cg = lane&15); b128 load covers 4 edges x 4 channels;
    // eg-butterfly (shfl_xor 16/32) completes channel sums.
    {
        int*    s_src = (int*)s_buf + wave * 64;             // per-wave [64] (1KB total)
        float4* s_w   = (float4*)(s_buf + 256) + wave * 64;  // per-wave [64] (4KB total)
        const float4* as4 = (const float4*)a_s_in;
        const float4* h4  = (const float4*)h_in;
        const int eg = lane >> 4, cg = lane & 15;
        for (int nd = 0; nd < 4; ++nd) {
            const int node = base + wave * 4 + nd;
            const int lo = rowptr[node], n = rowptr[node + 1] - lo;
            const float4 ad = ((const float4*)a_d_in)[node];
            float4 a0 = make_float4(0.f, 0.f, 0.f, 0.f);
            float4 a1 = a0, a2 = a0, a3 = a0;
            if (n <= 64) {
                float e0 = -1e30f, e1 = -1e30f, e2 = -1e30f, e3 = -1e30f;
                if (lane < n) {
                    int s = csr_src[lo + lane];
                    s_src[lane] = s;
                    float4 a = as4[s];
                    e0 = lrelu(a.x + ad.x); e1 = lrelu(a.y + ad.y);
                    e2 = lrelu(a.z + ad.z); e3 = lrelu(a.w + ad.w);
                }
                float M0 = wmax(e0), M1 = wmax(e1), M2 = wmax(e2), M3 = wmax(e3);
                float p0 = __expf(e0 - M0), p1 = __expf(e1 - M1);
                float p2 = __expf(e2 - M2), p3 = __expf(e3 - M3);   // inactive -> 0
                float iz0 = 1.f / (wsum(p0) + 1e-16f), iz1 = 1.f / (wsum(p1) + 1e-16f);
                float iz2 = 1.f / (wsum(p2) + 1e-16f), iz3 = 1.f / (wsum(p3) + 1e-16f);
                if (lane < n) s_w[lane] = make_float4(p0 * iz0, p1 * iz1, p2 * iz2, p3 * iz3);
                const int n8 = (n + 7) & ~7;
                if (lane >= n && lane < n8) {   // zero-weight padding, guard-free loop
                    s_src[lane] = s_src[0];
                    s_w[lane] = make_float4(0.f, 0.f, 0.f, 0.f);
                }
                for (int j = 0; j < n8; j += 8) {   // 8 edges in flight per iter
                    int sA = s_src[j + eg],     sB = s_src[j + 4 + eg];
                    float4 vA = h4[(size_t)sA * 16 + cg];
                    float4 vB = h4[(size_t)sB * 16 + cg];
                    float4 wA = s_w[j + eg],    wB = s_w[j + 4 + eg];
                    fma4(a0, vA, wA.x); fma4(a1, vA, wA.y); fma4(a2, vA, wA.z); fma4(a3, vA, wA.w);
                    fma4(a0, vB, wB.x); fma4(a1, vB, wB.y); fma4(a2, vB, wB.z); fma4(a3, vB, wB.w);
                }
            } else {
                // slow path (deg > 64): two-pass softmax, then chunked b128 gather
                float m0 = -1e30f, m1 = -1e30f, m2 = -1e30f, m3 = -1e30f;
                for (int j = lane; j < n; j += 64) {
                    int s = csr_src[lo + j];
                    float4 a = as4[s];
                    m0 = fmaxf(m0, lrelu(a.x + ad.x)); m1 = fmaxf(m1, lrelu(a.y + ad.y));
                    m2 = fmaxf(m2, lrelu(a.z + ad.z)); m3 = fmaxf(m3, lrelu(a.w + ad.w));
                }
                m0 = wmax(m0); m1 = wmax(m1); m2 = wmax(m2); m3 = wmax(m3);
                float z0 = 0.f, z1 = 0.f, z2 = 0.f, z3 = 0.f;
                for (int j = lane; j < n; j += 64) {
                    int s = csr_src[lo + j];
                    float4 a = as4[s];
                    z0 += __expf(lrelu(a.x + ad.x) - m0); z1 += __expf(lrelu(a.y + ad.y) - m1);
                    z2 += __expf(lrelu(a.z + ad.z) - m2); z3 += __expf(lrelu(a.w + ad.w) - m3);
                }
                float iz0 = 1.f / (wsum(z0) + 1e-16f), iz1 = 1.f / (wsum(z1) + 1e-16f);
                float iz2 = 1.f / (wsum(z2) + 1e-16f), iz3 = 1.f / (wsum(z3) + 1e-16f);
                for (int cb = 0; cb < n; cb += 64) {
                    int nn = n - cb; if (nn > 64) nn = 64;
                    if (lane < nn) {
                        int s = csr_src[lo + cb + lane];
                        s_src[lane] = s;
                        float4 a = as4[s];
                        s_w[lane] = make_float4(__expf(lrelu(a.x + ad.x) - m0) * iz0,
                                                __expf(lrelu(a.y + ad.y) - m1) * iz1,
                                                __expf(lrelu(a.z + ad.z) - m2) * iz2,
                                                __expf(lrelu(a.w + ad.w) - m3) * iz3);
                    }
                    const int nn8 = (nn + 7) & ~7;   // <= 64
                    if (lane >= nn && lane < nn8) {
                        s_src[lane] = s_src[0];
                        s_w[lane] = make_float4(0.f, 0.f, 0.f, 0.f);
                    }
                    for (int j = 0; j < nn8; j += 8) {
                        int sA = s_src[j + eg],     sB = s_src[j + 4 + eg];
                        float4 vA = h4[(size_t)sA * 16 + cg];
                        float4 vB = h4[(size_t)sB * 16 + cg];
                        float4 wA = s_w[j + eg],    wB = s_w[j + 4 + eg];
                        fma4(a0, vA, wA.x); fma4(a1, vA, wA.y); fma4(a2, vA, wA.z); fma4(a3, vA, wA.w);
                        fma4(a0, vB, wB.x); fma4(a1, vB, wB.y); fma4(a2, vB, wB.z); fma4(a3, vB, wB.w);
                    }
                }
            }
            // butterfly over eg bits (lanes 16/32 apart share channel group cg)
#pragma unroll
            for (int m = 16; m <= 32; m <<= 1) {
                a0.x += __shfl_xor(a0.x, m); a0.y += __shfl_xor(a0.y, m);
                a0.z += __shfl_xor(a0.z, m); a0.w += __shfl_xor(a0.w, m);
                a1.x += __shfl_xor(a1.x, m); a1.y += __shfl_xor(a1.y, m);
                a1.z += __shfl_xor(a1.z, m); a1.w += __shfl_xor(a1.w, m);
                a2.x += __shfl_xor(a2.x, m); a2.y += __shfl_xor(a2.y, m);
                a2.z += __shfl_xor(a2.z, m); a2.w += __shfl_xor(a2.w, m);
                a3.x += __shfl_xor(a3.x, m); a3.y += __shfl_xor(a3.y, m);
                a3.z += __shfl_xor(a3.z, m); a3.w += __shfl_xor(a3.w, m);
            }
            const int r = wave * 4 + nd;
            float4* si4 = (float4*)s_in;
            float4 outv = (eg == 0) ? a0 : (eg == 1) ? a1 : (eg == 2) ? a2 : a3;
            si4[r * 64 + lane] = outv;   // channel block eg*64 + 4*cg  == lane*4
        }
    }
    __syncthreads();   // gather scratch readers done; s_buf becomes dbuf tile store

    // ---- phase 2: GEMM1 mid = gelu(s_in @ W1eff + b1eff); 2 nodes x 4 f per thread;
    //      W1eff double-buffered: 16 tiles of 16x128 (8KB) alternating in s_buf halves.
    //      Next tile's global loads issue BEFORE computing current tile -> the barrier
    //      finds data resident (no vmcnt(0) stall at the tile boundary).
    const int fg = t & 31, ng2 = t >> 5;   // f = 4*fg.., nodes 2*ng2..2*ng2+1
    float4 acc1[2];
    acc1[0] = make_float4(0.f, 0.f, 0.f, 0.f);
    acc1[1] = make_float4(0.f, 0.f, 0.f, 0.f);
    {
        const float4* si4 = (const float4*)s_in;
        float4* sB4 = (float4*)s_buf;   // halves: [0..511] and [512..1023] float4s
        {   // prefetch tile 0 into half 0
            const float4* g0 = (const float4*)W1eff;
            sB4[t] = g0[t];
            sB4[t + 256] = g0[t + 256];
        }
        __syncthreads();
        for (int kt = 0; kt < 16; ++kt) {
            const int cur = (kt & 1) << 9;           // 0 or 512
            float4 pf0, pf1;
            const bool havepf = (kt + 1 < 16);
            if (havepf) {   // issue next tile's loads now; wait lands after compute
                const float4* gn = (const float4*)(W1eff + (size_t)(kt + 1) * 16 * DFFD);
                pf0 = gn[t];
                pf1 = gn[t + 256];
            }
#pragma unroll
            for (int k4 = 0; k4 < 4; ++k4) {
                float4 w0 = sB4[cur + (4 * k4 + 0) * 32 + fg];   // W1eff[k][4fg..4fg+3]
                float4 w1 = sB4[cur + (4 * k4 + 1) * 32 + fg];
                float4 w2 = sB4[cur + (4 * k4 + 2) * 32 + fg];
                float4 w3 = sB4[cur + (4 * k4 + 3) * 32 + fg];
#pragma unroll
                for (int i = 0; i < 2; ++i) {
                    float4 v = si4[(2 * ng2 + i) * 64 + kt * 4 + k4];   // half-wave uniform
                    acc1[i].x += v.x * w0.x + v.y * w1.x + v.z * w2.x + v.w * w3.x;
                    acc1[i].y += v.x * w0.y + v.y * w1.y + v.z * w2.y + v.w * w3.y;
                    acc1[i].z += v.x * w0.z + v.y * w1.z + v.z * w2.z + v.w * w3.z;
                    acc1[i].w += v.x * w0.w + v.y * w1.w + v.z * w2.w + v.w * w3.w;
                }
            }
            if (havepf) {
                const int nxt = ((kt + 1) & 1) << 9;
                sB4[nxt + t] = pf0;
                sB4[nxt + t + 256] = pf1;
            }
            __syncthreads();   // prefetch visible; all reads of cur done before overwrite
        }
    }
    {
        float4 bb = *(const float4*)(b1eff + 4 * fg);
#pragma unroll
        for (int i = 0; i < 2; ++i) {
            float dx = acc1[i].x + bb.x, dy = acc1[i].y + bb.y;
            float dz = acc1[i].z + bb.z, dw = acc1[i].w + bb.w;
            ((float4*)s_buf)[(2 * ng2 + i) * 32 + fg] = make_float4(
                0.5f * dx * (1.f + erff(dx * 0.70710678118654752f)),
                0.5f * dy * (1.f + erff(dy * 0.70710678118654752f)),
                0.5f * dz * (1.f + erff(dz * 0.70710678118654752f)),
                0.5f * dw * (1.f + erff(dw * 0.70710678118654752f)));
        }
    }
    __syncthreads();

    // ---- phase 3: GEMM2 + LN + residual + next-layer attdots; 4 nodes/wave ----
    {
        const int w = t >> 6;   // wave w -> nodes 4w..4w+3, lane = channel
        float acc[4];
#pragma unroll
        for (int i = 0; i < 4; ++i) acc[i] = 0.f;
        const float4* sm4 = (const float4*)s_buf;
#pragma unroll 4
        for (int k4 = 0; k4 < 32; ++k4) {
            float w0 = W2[(4 * k4 + 0) * HIDD + lane];
            float w1 = W2[(4 * k4 + 1) * HIDD + lane];
            float w2 = W2[(4 * k4 + 2) * HIDD + lane];
            float w3 = W2[(4 * k4 + 3) * HIDD + lane];
#pragma unroll
            for (int i = 0; i < 4; ++i) {
                float4 v = sm4[(4 * w + i) * 32 + k4];   // wave-uniform broadcast
                acc[i] += v.x * w0 + v.y * w1 + v.z * w2 + v.w * w3;
            }
        }
        const float b2c = b2[lane], gc = ln_g[lane], bbc = ln_b[lane];
        float wr[8];
#pragma unroll
        for (int r = 0; r < 8; ++r) wr[r] = 0.f;
        if (ws_next) {
#pragma unroll
            for (int r = 0; r < 8; ++r) wr[r] = ws_next[r * 64 + lane];
        }
#pragma unroll
        for (int i = 0; i < 4; ++i) {
            int node = base + 4 * w + i;
            float d = acc[i] + b2c;
            float mean = wsum(d) * (1.0f / 64.0f);
            float dd = d - mean;
            float var = wsum(dd * dd) * (1.0f / 64.0f);
            float hv = h_in[(size_t)node * HIDD + lane] + dd * rsqrtf(var + 1e-5f) * gc + bbc;
            h_out[(size_t)node * HIDD + lane] = hv;
            if (ws_next) {
                float s0 = wsum(hv * wr[0]), s1 = wsum(hv * wr[1]);
                float s2 = wsum(hv * wr[2]), s3 = wsum(hv * wr[3]);
                float s4 = wsum(hv * wr[4]), s5 = wsum(hv * wr[5]);
                float s6 = wsum(hv * wr[6]), s7 = wsum(hv * wr[7]);
                if (lane == 0) {
                    ((float4*)a_s_out)[node] = make_float4(s0, s1, s2, s3);
                    ((float4*)a_d_out)[node] = make_float4(s4, s5, s6, s7);
                }
            }
        }
    }
}

extern "C" void kernel_launch(void* const* d_in, const int* in_sizes, int n_in,
                              void* d_out, int out_size, void* d_ws, size_t ws_size,
                              hipStream_t stream) {
    const float* x       = (const float*)d_in[0];
    const int*   ei      = (const int*)d_in[1];
    const float* We      = (const float*)d_in[2];
    const float* be      = (const float*)d_in[3];
    const float* Wc      = (const float*)d_in[4];
    const float* att_src = (const float*)d_in[5];
    const float* att_dst = (const float*)d_in[6];
    const float* bc      = (const float*)d_in[7];
    const float* W1      = (const float*)d_in[8];
    const float* b1      = (const float*)d_in[9];
    const float* W2      = (const float*)d_in[10];
    const float* b2      = (const float*)d_in[11];
    const float* ln_g    = (const float*)d_in[12];
    const float* ln_b    = (const float*)d_in[13];

    char* ws = (char*)d_ws;
    size_t off = 0;
    auto alloc = [&](size_t bytes) -> void* {
        void* p = ws + off; off += (bytes + 255) & ~(size_t)255; return p;
    };
    float* h0      = (float*)alloc((size_t)NN * HIDD * 4);
    float* h1      = (float*)alloc((size_t)NN * HIDD * 4);
    float* as0     = (float*)alloc((size_t)NN * NH * 4);
    float* ad0     = (float*)alloc((size_t)NN * NH * 4);
    float* as1     = (float*)alloc((size_t)NN * NH * 4);
    float* ad1     = (float*)alloc((size_t)NN * NH * 4);
    float* ws_all  = (float*)alloc((size_t)NL * 8 * 64 * 4);
    float* W1eff   = (float*)alloc((size_t)NL * HC * DFFD * 4);
    float* b1eff   = (float*)alloc((size_t)NL * DFFD * 4);
    int*   deg     = (int*)alloc((size_t)NN * 4);
    int*   rowptr  = (int*)alloc((size_t)(NN + 1) * 4);
    int*   cursor  = (int*)alloc((size_t)NN * 4);
    int*   csr_src = (int*)alloc((size_t)(NE + NN) * 4);
    (void)ws_size; (void)in_sizes; (void)n_in; (void)out_size;

    ws_kernel<<<8, 256, 0, stream>>>(Wc, att_src, att_dst, ws_all);
    w1eff_kernel<<<NL * 256, 128, 0, stream>>>(Wc, W1, W1eff);
    b1eff_kernel<<<NL, 128, 0, stream>>>(bc, W1, b1, b1eff);
    init_deg<<<(NN + 255) / 256, 256, 0, stream>>>(deg, cursor);
    embed_kernel<<<NN / 16, 256, 0, stream>>>(x, We, be, ws_all, h0, as0, ad0);
    count_edges<<<(NE + 255) / 256, 256, 0, stream>>>(ei, deg);
    scan_kernel<<<1, 1024, 0, stream>>>(deg, rowptr);
    scatter_edges<<<(NE + NN + 255) / 256, 256, 0, stream>>>(ei, rowptr, cursor, csr_src);

    for (int l = 0; l < NL; ++l) {
        const float* hi  = (l & 1) ? h1  : h0;
        const float* asi = (l & 1) ? as1 : as0;
        const float* adi = (l & 1) ? ad1 : ad0;
        float* ho  = (l == NL - 1) ? (float*)d_out : ((l & 1) ? h0 : h1);
        float* aso = (l & 1) ? as0 : as1;
        float* ado = (l & 1) ? ad0 : ad1;
        layer_kernel<<<NN / NPB, 256, 0, stream>>>(hi, asi, adi, rowptr, csr_src,
            W1eff + (size_t)l * HC * DFFD, b1eff + (size_t)l * DFFD,
            W2 + (size_t)l * DFFD * HIDD, b2 + (size_t)l * HIDD,
            ln_g + (size_t)l * HIDD, ln_b + (size_t)l * HIDD,
            (l + 1 < NL) ? (ws_all + (size_t)(l + 1) * 8 * 64) : (const float*)nullptr,
            ho, aso, ado);
    }
}